// Round 1
// baseline (7085.751 us; speedup 1.0000x reference)
//
#include <hip/hip_runtime.h>
#include <math.h>

// Problem constants
#define TT 512
#define BB 64
#define EE 300
#define HD 256
#define KK 20
#define NG 1024        // gate rows per direction

// LSTM kernel geometry: 64 blocks = 4 row-domains (16 rows) x 16 dim-groups (16 dims),
// each block handles BOTH directions (fwd+bwd) to hide exchange latency under compute.
#define HS 260                         // LDS h row stride (floats), padded (bank-conflict-free)
#define HOFF 32768                     // W slice: 2 dirs * 256 k * 64 (16 dims x 4 gates) floats
#define LDS_FLOATS (HOFF + 16 * HS)    // 36928 floats = 147712 B  (< proven 151808 B)

// Relaxed agent-scope atomics = cache-bypassing LLC ops (no fences anywhere;
// W/P stay cache-resident). Proven correct in prior rounds (absmax 0).
__device__ __forceinline__ int ldg_llc_i(const int* p) {
    return __hip_atomic_load(p, __ATOMIC_RELAXED, __HIP_MEMORY_SCOPE_AGENT);
}
__device__ __forceinline__ void stg_llc_i(int* p, int v) {
    __hip_atomic_store(p, v, __ATOMIC_RELAXED, __HIP_MEMORY_SCOPE_AGENT);
}
__device__ __forceinline__ unsigned long long ldg_llc_u64(const unsigned long long* p) {
    return __hip_atomic_load(p, __ATOMIC_RELAXED, __HIP_MEMORY_SCOPE_AGENT);
}
__device__ __forceinline__ void stg_llc_f(float* p, float v) {
    __hip_atomic_store(p, v, __ATOMIC_RELAXED, __HIP_MEMORY_SCOPE_AGENT);
}

// ============================================================
// K1: fused embedding-gather + input projection GEMM (fp32)
// P layout: [slot][row(64)][gate(1024)] (gate innermost).  (unchanged, proven)
// ============================================================
__global__ __launch_bounds__(256) void proj_kernel(
    const int* __restrict__ sentence, const float* __restrict__ embed,
    const float* __restrict__ Wf_ih, const float* __restrict__ bf,
    const float* __restrict__ Wb_ih, const float* __restrict__ bb,
    float* __restrict__ Pf, float* __restrict__ Pb, int t0f, int t0b)
{
    __shared__ float As[32][BB];
    __shared__ float Ws[32][64];
    const int s   = blockIdx.x;
    const int gb  = blockIdx.y;
    const int dir = gb >> 4;
    const int g0  = (gb & 15) * 64;
    const int tg  = dir ? (t0b + s) : (t0f + s);
    const int tid = threadIdx.x;
    const int tx = tid & 15, ty = tid >> 4;

    const int lrow = tid >> 2;
    const int kq   = tid & 3;
    const int word = sentence[lrow * TT + tg];
    const float* arow = embed + (size_t)word * EE;
    const float* Wih  = dir ? Wb_ih : Wf_ih;
    const float* bias = dir ? bb : bf;
    const float* wrow = Wih + (size_t)(g0 + lrow) * EE;

    float acc[4][4] = {};
    for (int k0 = 0; k0 < EE; k0 += 32) {
        __syncthreads();
        #pragma unroll
        for (int u = 0; u < 8; ++u) {
            const int k  = kq * 8 + u;
            const int kk = k0 + k;
            const bool ok = (kk < EE);
            As[k][lrow] = ok ? arow[kk] : 0.f;
            Ws[k][lrow] = ok ? wrow[kk] : 0.f;
        }
        __syncthreads();
        #pragma unroll
        for (int k = 0; k < 32; ++k) {
            const float4 a = *(const float4*)&As[k][ty * 4];
            const float4 w = *(const float4*)&Ws[k][tx * 4];
            acc[0][0] += a.x*w.x; acc[0][1] += a.x*w.y; acc[0][2] += a.x*w.z; acc[0][3] += a.x*w.w;
            acc[1][0] += a.y*w.x; acc[1][1] += a.y*w.y; acc[1][2] += a.y*w.z; acc[1][3] += a.y*w.w;
            acc[2][0] += a.z*w.x; acc[2][1] += a.z*w.y; acc[2][2] += a.z*w.z; acc[2][3] += a.z*w.w;
            acc[3][0] += a.w*w.x; acc[3][1] += a.w*w.y; acc[3][2] += a.w*w.z; acc[3][3] += a.w*w.w;
        }
    }
    float* Pd = (dir ? Pb : Pf) + (size_t)s * BB * NG;
    const float4 bv = *(const float4*)&bias[g0 + tx * 4];
    #pragma unroll
    for (int i = 0; i < 4; ++i) {
        float4 v;
        v.x = acc[i][0] + bv.x; v.y = acc[i][1] + bv.y;
        v.z = acc[i][2] + bv.z; v.w = acc[i][3] + bv.w;
        *(float4*)(Pd + (size_t)(ty * 4 + i) * NG + g0 + tx * 4) = v;
    }
}

// ============================================================
// K2: dual-direction 2D-partitioned bidirectional LSTM (software-pipelined).
// 64 blocks x 256 threads. blk&3 = row-domain (16 batch rows), blk>>2 = dim-group
// (16 dims). Each block runs BOTH dirs for its (rows x dims) tile:
//   per step:  [write prefetched fwd-h regs->LDS | poll bwd flags] -> barrier ->
//              issue bwd-h LLC loads -> GEMV fwd -> cell -> publish+flag fwd ->
//              [write bwd-h regs->LDS | poll fwd flags] -> barrier ->
//              issue next fwd-h LLC loads -> GEMV bwd -> cell -> publish+flag bwd.
// Each dir's flag-wait + LLC h-load latency hides under the OTHER dir's GEMV.
// W slice (2 dirs x 64 gate-rows x 256 k = 128 KB) preloaded to LDS once.
// Thread (gl = tid&15 -> dim, rs = tid>>4 -> row): 4 gates x 1 row per dir,
// c state in registers. Flag protocol + parity double-buffer identical to the
// proven single-dir version (per direction).
// ============================================================
__global__ __launch_bounds__(256) void lstm_kernel(
    const float* __restrict__ Pf, const float* __restrict__ Pb,
    const float* __restrict__ Wf_hh, const float* __restrict__ Wb_hh,
    const int* __restrict__ lengths,
    float* __restrict__ HF, float* __restrict__ HB,
    float* __restrict__ hx,      // [parity][dir][domain4][row 16][k 256]
    float* __restrict__ cbuf,    // [dir][dim 256][row 64]
    int* __restrict__ flags,     // [dir*4+domain][16] (one 64B line each)
    int step0, int nsteps)
{
    extern __shared__ float lds[];
    const int blk    = blockIdx.x;
    const int domain = blk & 3;          // row-group
    const int j      = blk >> 2;         // dim-group 0..15
    const int tid    = threadIdx.x;
    const int gl     = tid & 15;         // dim within group
    const int rs     = tid >> 4;         // row 0..15
    const int dg     = j * 16 + gl;      // global dim 0..255
    const int grow   = domain * 16 + rs; // global batch row

    // ---- preload W slices (both dirs): lds[d*16384 + k*64 + (gll*4+gt)]
    // per outer iter: uniform gate-row c, threads load k=tid (coalesced 1KB).
    // LDS write is 32-way bank-conflicted (stride-64 dwords) but runs once
    // per dispatch (~8us) — not worth a swizzle on the GEMV hot path.
    {
        const float* W2[2] = { Wf_hh, Wb_hh };
        #pragma unroll
        for (int d = 0; d < 2; ++d) {
            const float* Wh = W2[d];
            for (int e = tid; e < 16384; e += 256) {
                const int k = e & 255;       // = tid
                const int c = e >> 8;        // 0..63 local gate-row
                const int gll = c >> 2, gt = c & 3;
                lds[d * 16384 + k * 64 + c] =
                    Wh[(size_t)(gt * 256 + j * 16 + gll) * HD + k];
            }
        }
    }

    const int len = lengths[grow];
    float c_f = cbuf[(size_t)(0 * HD + dg) * BB + grow];
    float c_b = cbuf[(size_t)(1 * HD + dg) * BB + grow];

    int* flagF = flags + (0 * 4 + domain) * 16;
    int* flagB = flags + (1 * 4 + domain) * 16;
    const int* pollF = flagF + (tid & 15);
    const int* pollB = flagB + (tid & 15);

    // ---- prologue: fwd h(step0-1) -> registers (parity (step0+1)&1)
    if (tid < 64) {
        int v;
        do { v = ldg_llc_i(pollF); } while (!__all(v >= step0));
    }
    __syncthreads();    // covers W preload LDS writes + prologue poll

    unsigned long long hreg[8];
    {
        const unsigned long long* src = (const unsigned long long*)
            (hx + (((size_t)(((step0 + 1) & 1) * 2 + 0) * 4 + domain) * 16 + rs) * 256);
        #pragma unroll
        for (int it = 0; it < 8; ++it) hreg[it] = ldg_llc_u64(&src[gl + 16 * it]);
    }

    for (int u = 0; u < nsteps; ++u) {
        const int gs = step0 + u;
        const int pp = TT - 1 - gs;          // original time index for bwd

        // P terms (h-independent): issue early, consumed after GEMVs
        const float* Ppf = Pf + ((size_t)u * BB + grow) * NG + dg;
        const float* Ppb = Pb + ((size_t)(nsteps - 1 - u) * BB + grow) * NG + dg;
        const float pfi = Ppf[0], pff = Ppf[256], pfg = Ppf[512], pfo = Ppf[768];
        const float pbi = Ppb[0], pbf = Ppb[256], pbg = Ppb[512], pbo = Ppb[768];

        // ===== A phase: forward =====
        int fv = 0;
        if (tid < 64) fv = ldg_llc_i(pollB);     // speculative early flag read
        // staged fwd h (prefetched last B-phase) -> LDS
        #pragma unroll
        for (int it = 0; it < 8; ++it) {
            union { unsigned long long u64v; float f[2]; } cv; cv.u64v = hreg[it];
            float2 v2; v2.x = cv.f[0]; v2.y = cv.f[1];
            *(float2*)&lds[HOFF + rs * HS + 2 * (gl + 16 * it)] = v2;
        }
        if (tid < 64) {
            int v = fv;
            while (!__all(v >= gs)) v = ldg_llc_i(pollB);
        }
        __syncthreads();
        // issue bwd h loads (h_b(gs-1), parity (gs+1)&1) — fly under GEMV fwd
        {
            const unsigned long long* src = (const unsigned long long*)
                (hx + (((size_t)(((gs + 1) & 1) * 2 + 1) * 4 + domain) * 16 + rs) * 256);
            #pragma unroll
            for (int it = 0; it < 8; ++it) hreg[it] = ldg_llc_u64(&src[gl + 16 * it]);
        }
        // GEMV fwd: 4 gates x 1 row over k=256 (k-ascending fmaf: bit-exact vs prior)
        float ai = 0.f, af = 0.f, ag = 0.f, ao = 0.f;
        {
            const float* Wl = lds + (gl << 2);
            const float* hr = lds + HOFF + rs * HS;
            #pragma unroll 4
            for (int k = 0; k < HD; k += 4) {
                const float4 w0 = *(const float4*)(Wl + (size_t)(k + 0) * 64);
                const float4 w1 = *(const float4*)(Wl + (size_t)(k + 1) * 64);
                const float4 w2 = *(const float4*)(Wl + (size_t)(k + 2) * 64);
                const float4 w3 = *(const float4*)(Wl + (size_t)(k + 3) * 64);
                const float4 h4 = *(const float4*)(hr + k);
                ai = fmaf(w0.x, h4.x, ai); af = fmaf(w0.y, h4.x, af);
                ag = fmaf(w0.z, h4.x, ag); ao = fmaf(w0.w, h4.x, ao);
                ai = fmaf(w1.x, h4.y, ai); af = fmaf(w1.y, h4.y, af);
                ag = fmaf(w1.z, h4.y, ag); ao = fmaf(w1.w, h4.y, ao);
                ai = fmaf(w2.x, h4.z, ai); af = fmaf(w2.y, h4.z, af);
                ag = fmaf(w2.z, h4.z, ag); ao = fmaf(w2.w, h4.z, ao);
                ai = fmaf(w3.x, h4.w, ai); af = fmaf(w3.y, h4.w, af);
                ag = fmaf(w3.z, h4.w, ag); ao = fmaf(w3.w, h4.w, ao);
            }
        }
        const float igf = 1.f / (1.f + expf(-(ai + pfi)));
        const float fgf = 1.f / (1.f + expf(-(af + pff)));
        const float ogf = 1.f / (1.f + expf(-(ao + pfo)));
        const float gtf = tanhf(ag + pfg);
        c_f = fgf * c_f + igf * gtf;
        const float hnf = ogf * tanhf(c_f);
        // publish fwd h (parity gs&1) -> LLC
        stg_llc_f(&hx[(((size_t)((gs & 1) * 2 + 0) * 4 + domain) * 16 + rs) * 256 + dg], hnf);
        __syncthreads();   // vmcnt(0): h complete at LLC before flag
        if (tid == 0) stg_llc_i(&flagF[j], gs + 1);
        HF[((size_t)gs * HD + dg) * BB + grow] = hnf;   // lazy, after flag

        // ===== B phase: backward =====
        int bv = 0;
        if (tid < 64) bv = ldg_llc_i(pollF);     // speculative early flag read
        // staged bwd h -> LDS (safe: A3 barrier separated fwd GEMV readers)
        #pragma unroll
        for (int it = 0; it < 8; ++it) {
            union { unsigned long long u64v; float f[2]; } cv; cv.u64v = hreg[it];
            float2 v2; v2.x = cv.f[0]; v2.y = cv.f[1];
            *(float2*)&lds[HOFF + rs * HS + 2 * (gl + 16 * it)] = v2;
        }
        if (tid < 64) {
            int v = bv;
            while (!__all(v >= gs + 1)) v = ldg_llc_i(pollF);
        }
        __syncthreads();
        // issue fwd h loads for step gs+1 (h_f(gs), parity gs&1) — fly under GEMV bwd
        {
            const unsigned long long* src = (const unsigned long long*)
                (hx + (((size_t)((gs & 1) * 2 + 0) * 4 + domain) * 16 + rs) * 256);
            #pragma unroll
            for (int it = 0; it < 8; ++it) hreg[it] = ldg_llc_u64(&src[gl + 16 * it]);
        }
        // GEMV bwd
        float bi = 0.f, bf2 = 0.f, bg = 0.f, bo = 0.f;
        {
            const float* Wl = lds + 16384 + (gl << 2);
            const float* hr = lds + HOFF + rs * HS;
            #pragma unroll 4
            for (int k = 0; k < HD; k += 4) {
                const float4 w0 = *(const float4*)(Wl + (size_t)(k + 0) * 64);
                const float4 w1 = *(const float4*)(Wl + (size_t)(k + 1) * 64);
                const float4 w2 = *(const float4*)(Wl + (size_t)(k + 2) * 64);
                const float4 w3 = *(const float4*)(Wl + (size_t)(k + 3) * 64);
                const float4 h4 = *(const float4*)(hr + k);
                bi  = fmaf(w0.x, h4.x, bi);  bf2 = fmaf(w0.y, h4.x, bf2);
                bg  = fmaf(w0.z, h4.x, bg);  bo  = fmaf(w0.w, h4.x, bo);
                bi  = fmaf(w1.x, h4.y, bi);  bf2 = fmaf(w1.y, h4.y, bf2);
                bg  = fmaf(w1.z, h4.y, bg);  bo  = fmaf(w1.w, h4.y, bo);
                bi  = fmaf(w2.x, h4.z, bi);  bf2 = fmaf(w2.y, h4.z, bf2);
                bg  = fmaf(w2.z, h4.z, bg);  bo  = fmaf(w2.w, h4.z, bo);
                bi  = fmaf(w3.x, h4.w, bi);  bf2 = fmaf(w3.y, h4.w, bf2);
                bg  = fmaf(w3.z, h4.w, bg);  bo  = fmaf(w3.w, h4.w, bo);
            }
        }
        const float igb = 1.f / (1.f + expf(-(bi + pbi)));
        const float fgb = 1.f / (1.f + expf(-(bf2 + pbf)));
        const float ogb = 1.f / (1.f + expf(-(bo + pbo)));
        const float gtb = tanhf(bg + pbg);
        const float cnb = fgb * c_b + igb * gtb;
        float hnb = ogb * tanhf(cnb);
        const bool vOK = (pp < len);         // bwd rows inactive until p < len
        c_b = vOK ? cnb : c_b;
        hnb = vOK ? hnb : 0.f;
        stg_llc_f(&hx[(((size_t)((gs & 1) * 2 + 1) * 4 + domain) * 16 + rs) * 256 + dg], hnb);
        __syncthreads();   // vmcnt(0): h complete at LLC before flag
        if (tid == 0) stg_llc_i(&flagB[j], gs + 1);
        HB[((size_t)pp * HD + dg) * BB + grow] = hnb;   // lazy, after flag
    }

    cbuf[(size_t)(0 * HD + dg) * BB + grow] = c_f;
    cbuf[(size_t)(1 * HD + dg) * BB + grow] = c_b;
}

// ============================================================
// K3: emissions = [hf|hb] @ W_out^T + b_out -> emis[t][b][20]
// H layout [t][d][b].  (unchanged, proven)
// ============================================================
__global__ __launch_bounds__(256) void emis_kernel(
    const float* __restrict__ HF, const float* __restrict__ HB,
    const float* __restrict__ W_out, const float* __restrict__ b_out,
    float* __restrict__ emis)
{
    const int t = blockIdx.x;
    const int b = threadIdx.x & 63;
    int jg = threadIdx.x >> 6;
    jg = __builtin_amdgcn_readfirstlane(jg);

    float acc[5];
    #pragma unroll
    for (int u = 0; u < 5; ++u) acc[u] = b_out[jg + 4 * u];

    const float* hf = HF + (size_t)t * HD * BB + b;
    const float* hb = HB + (size_t)t * HD * BB + b;
    for (int k = 0; k < HD; ++k) {
        const float hv = hf[(size_t)k * BB];
        #pragma unroll
        for (int u = 0; u < 5; ++u)
            acc[u] = fmaf(hv, W_out[(size_t)(jg + 4 * u) * 512 + k], acc[u]);
    }
    for (int k = 0; k < HD; ++k) {
        const float hv = hb[(size_t)k * BB];
        #pragma unroll
        for (int u = 0; u < 5; ++u)
            acc[u] = fmaf(hv, W_out[(size_t)(jg + 4 * u) * 512 + HD + k], acc[u]);
    }
    #pragma unroll
    for (int u = 0; u < 5; ++u)
        emis[((size_t)t * BB + b) * KK + jg + 4 * u] = acc[u];
}

// ============================================================
// K4: Viterbi per batch row; exact first-max argmax; bp in LDS. (unchanged)
// ============================================================
__global__ __launch_bounds__(64) void viterbi_kernel(
    const float* __restrict__ emis, const int* __restrict__ lengths,
    const float* __restrict__ trans, const int* __restrict__ stop_id_p,
    float* __restrict__ out)
{
    __shared__ float tr[KK * KK];
    __shared__ float delta[KK], nd[KK];
    __shared__ unsigned char bp[TT][KK];
    const int b = blockIdx.x;
    const int tid = threadIdx.x;
    for (int i = tid; i < KK * KK; i += 64) tr[i] = trans[i];
    if (tid < KK) delta[tid] = 0.f;
    const int len = lengths[b];
    __syncthreads();

    for (int t = 0; t < TT; ++t) {
        if (tid < KK) {
            if (t < len) {
                float best = delta[0] + tr[tid * KK + 0];
                int am = 0;
                for (int p2 = 1; p2 < KK; ++p2) {
                    const float v = delta[p2] + tr[tid * KK + p2];
                    if (v > best) { best = v; am = p2; }
                }
                nd[tid] = best + emis[((size_t)t * BB + b) * KK + tid];
                bp[t][tid] = (unsigned char)am;
            } else {
                nd[tid] = delta[tid];
                bp[t][tid] = (unsigned char)tid;
            }
        }
        __syncthreads();
        if (tid < KK) delta[tid] = nd[tid];
        __syncthreads();
    }

    if (tid == 0) {
        const int stop_id = *stop_id_p;
        float best = delta[0] + tr[stop_id * KK + 0];
        int bl = 0;
        for (int jx = 1; jx < KK; ++jx) {
            const float v = delta[jx] + tr[stop_id * KK + jx];
            if (v > best) { best = v; bl = jx; }
        }
        out[b] = best;
        float* pout = out + BB + (size_t)b * (TT + 1);
        pout[TT] = (float)bl;
        int tag = bl;
        for (int t = TT - 1; t >= 0; --t) {
            tag = bp[t][tag];
            pout[t] = (float)tag;
        }
    }
}

// ============================================================
extern "C" void kernel_launch(void* const* d_in, const int* in_sizes, int n_in,
                              void* d_out, int out_size, void* d_ws, size_t ws_size,
                              hipStream_t stream) {
    const int*   sentence = (const int*)d_in[0];
    const int*   lengths  = (const int*)d_in[1];
    const int*   stop_id  = (const int*)d_in[3];
    const float* embed    = (const float*)d_in[4];
    const float* Wf_ih    = (const float*)d_in[5];
    const float* Wf_hh    = (const float*)d_in[6];
    const float* bf       = (const float*)d_in[7];
    const float* Wb_ih    = (const float*)d_in[8];
    const float* Wb_hh    = (const float*)d_in[9];
    const float* bb       = (const float*)d_in[10];
    const float* W_out    = (const float*)d_in[11];
    const float* b_out    = (const float*)d_in[12];
    const float* trans    = (const float*)d_in[13];
    float* out = (float*)d_out;

    const size_t hf_elems   = (size_t)TT * HD * BB;
    const size_t emis_elems = (size_t)TT * BB * KK;
    const size_t hx_elems   = (size_t)2 * 2 * 4 * 16 * HD;   // 65536
    const size_t cbuf_elems = (size_t)2 * HD * BB;           // 32768
    const size_t flag_elems = (size_t)8 * 16;
    const size_t fixed_bytes = (2 * hf_elems + emis_elems + hx_elems + cbuf_elems + flag_elems) * 4;

    int CH = 0;
    const int cands[6] = {256, 128, 64, 32, 16, 8};
    for (int i = 0; i < 6; ++i) {
        const size_t need = fixed_bytes + 2ull * cands[i] * BB * NG * 4;
        if (need <= ws_size) { CH = cands[i]; break; }
    }
    if (CH == 0) return;

    float* Pf    = (float*)d_ws;
    float* Pb    = Pf + (size_t)CH * BB * NG;
    float* HF    = Pb + (size_t)CH * BB * NG;
    float* HB    = HF + hf_elems;
    float* emis  = HB + hf_elems;
    float* hx    = emis + emis_elems;
    float* cbuf  = hx + hx_elems;
    int*   flags = (int*)(cbuf + cbuf_elems);

    // allow >64KB dynamic LDS (idempotent host call; not a stream op)
    hipFuncSetAttribute((const void*)lstm_kernel,
                        hipFuncAttributeMaxDynamicSharedMemorySize,
                        LDS_FLOATS * 4);

    // zero hx (both parities), cbuf, flags — contiguous region
    hipMemsetAsync(hx, 0, (hx_elems + cbuf_elems + flag_elems) * 4, stream);

    const int nch = TT / CH;
    for (int c = 0; c < nch; ++c) {
        const int t0f = c * CH;
        const int t0b = TT - (c + 1) * CH;
        proj_kernel<<<dim3(CH, 32), 256, 0, stream>>>(
            sentence, embed, Wf_ih, bf, Wb_ih, bb, Pf, Pb, t0f, t0b);
        lstm_kernel<<<dim3(64), 256, LDS_FLOATS * 4, stream>>>(
            Pf, Pb, Wf_hh, Wb_hh, lengths, HF, HB, hx, cbuf, flags, c * CH, CH);
    }
    emis_kernel<<<dim3(TT), 256, 0, stream>>>(HF, HB, W_out, b_out, emis);
    viterbi_kernel<<<dim3(BB), 64, 0, stream>>>(emis, lengths, trans, stop_id, out);
}